// Round 5
// baseline (335.084 us; speedup 1.0000x reference)
//
#include <hip/hip_runtime.h>
#include <hip/hip_fp16.h>

#define NH 32
#define NKVH 8
#define HD 128
#define GRP 4
#define SCALE 0.08838834764831845f
#define LOG2E 1.4426950408889634f

typedef __attribute__((ext_vector_type(8))) __bf16 bf16x8;
typedef __attribute__((ext_vector_type(4))) float f32x4;
typedef __attribute__((ext_vector_type(8))) unsigned short ushort8;

__device__ inline unsigned short f2bf(float x) {
  unsigned int u = __float_as_uint(x);
  u += 0x7fffu + ((u >> 16) & 1u);   // RNE
  return (unsigned short)(u >> 16);
}

__device__ inline float dpp_max16(float x) {
  x = fmaxf(x, __int_as_float(__builtin_amdgcn_mov_dpp(__float_as_int(x), 0xB1, 0xF, 0xF, true)));
  x = fmaxf(x, __int_as_float(__builtin_amdgcn_mov_dpp(__float_as_int(x), 0x4E, 0xF, 0xF, true)));
  x = fmaxf(x, __int_as_float(__builtin_amdgcn_mov_dpp(__float_as_int(x), 0x141, 0xF, 0xF, true)));
  x = fmaxf(x, __int_as_float(__builtin_amdgcn_mov_dpp(__float_as_int(x), 0x140, 0xF, 0xF, true)));
  return x;
}
__device__ inline float dpp_sum16(float x) {
  x += __int_as_float(__builtin_amdgcn_mov_dpp(__float_as_int(x), 0xB1, 0xF, 0xF, true));
  x += __int_as_float(__builtin_amdgcn_mov_dpp(__float_as_int(x), 0x4E, 0xF, 0xF, true));
  x += __int_as_float(__builtin_amdgcn_mov_dpp(__float_as_int(x), 0x141, 0xF, 0xF, true));
  x += __int_as_float(__builtin_amdgcn_mov_dpp(__float_as_int(x), 0x140, 0xF, 0xF, true));
  return x;
}

// ---------------- fused pre-pass ----------------
// Kp[kvh][l][d]  bf16 row-major;  Vp[kvh][d][l]  bf16 transposed.
__global__ __launch_bounds__(256) void prep_kernel(
    const float* __restrict__ k, const float* __restrict__ v,
    const float* __restrict__ kc, const float* __restrict__ vc,
    const int* __restrict__ slots,
    unsigned short* __restrict__ Kp, unsigned short* __restrict__ Vp,
    int ctx, int L, int kblocks)
{
  if ((int)blockIdx.x < kblocks) {
    const int idx = blockIdx.x * 256 + threadIdx.x;     // (kvh, l, 16-d chunk)
    const int L8  = L * 8;
    const int kvh = idx / L8;
    const int rem = idx - kvh * L8;
    const int l   = rem >> 3;
    const int c16 = idx & 7;
    const float* src = (l < ctx)
        ? kc + ((size_t)slots[l] * NKVH + kvh) * HD + c16 * 16
        : k + (size_t)(l - ctx) * (NKVH * HD) + kvh * HD + c16 * 16;
    float4 f[4];
#pragma unroll
    for (int i = 0; i < 4; ++i) f[i] = ((const float4*)src)[i];
    ushort8 w0, w1;
    w0[0]=f2bf(f[0].x); w0[1]=f2bf(f[0].y); w0[2]=f2bf(f[0].z); w0[3]=f2bf(f[0].w);
    w0[4]=f2bf(f[1].x); w0[5]=f2bf(f[1].y); w0[6]=f2bf(f[1].z); w0[7]=f2bf(f[1].w);
    w1[0]=f2bf(f[2].x); w1[1]=f2bf(f[2].y); w1[2]=f2bf(f[2].z); w1[3]=f2bf(f[2].w);
    w1[4]=f2bf(f[3].x); w1[5]=f2bf(f[3].y); w1[6]=f2bf(f[3].z); w1[7]=f2bf(f[3].w);
    unsigned short* dst = Kp + ((size_t)kvh * L + l) * HD + c16 * 16;
    *(ushort8*)(dst + 0) = w0;
    *(ushort8*)(dst + 8) = w1;
  } else {
    __shared__ __align__(16) unsigned short VT[128 * 72];
    const int b   = blockIdx.x - kblocks;               // (kvh, 64-l tile)
    const int ntv = L >> 6;
    const int kvh = b / ntv;
    const int t   = b - kvh * ntv;
    const int tid = threadIdx.x;
    const int l   = tid >> 2;
    const int ds  = tid & 3;
    const int lg  = t * 64 + l;
    const float* sp = (lg < ctx)
        ? vc + ((size_t)slots[lg] * NKVH + kvh) * HD
        : v + (size_t)(lg - ctx) * (NKVH * HD) + kvh * HD;
    sp += ds * 32;
    float4 f[8];
#pragma unroll
    for (int i = 0; i < 8; ++i) f[i] = ((const float4*)sp)[i];
#pragma unroll
    for (int i = 0; i < 8; ++i) {
      const int d0 = ds * 32 + i * 4;
      VT[(d0+0)*72 + l] = f2bf(f[i].x);
      VT[(d0+1)*72 + l] = f2bf(f[i].y);
      VT[(d0+2)*72 + l] = f2bf(f[i].z);
      VT[(d0+3)*72 + l] = f2bf(f[i].w);
    }
    __syncthreads();
    const int d   = tid >> 1;
    const int seg = tid & 1;
    unsigned short* dst = Vp + ((size_t)kvh * HD + d) * L + t * 64 + seg * 32;
#pragma unroll
    for (int i = 0; i < 4; ++i)
      *(ushort8*)(dst + i * 8) = *(const ushort8*)&VT[d * 72 + seg * 32 + i * 8];
  }
}

// ---------------- attention: 4 waves share 32 q-rows, split the key dim ----------------
// Wave w handles key strips [t*128 + w*32, +32). No LDS K/V staging: fragments are
// b128 global loads from the fragment-ordered ws (L2-resident; kvh==XCD affinity).
// No __syncthreads in the loop. Flash-decoding merge across waves at the end.
#define PSTR 40     // P row stride (halfs): 32 + 8; keeps b128 pf reads 16B-aligned
#define OSTR 136    // fp16 O-buf row stride: 272B -> 68 dw = 4 mod 32 (2-way free)

__global__ __launch_bounds__(256, 2) void attn_kernel(
    const float* __restrict__ q,
    const unsigned short* __restrict__ Kp, const unsigned short* __restrict__ Vp,
    float* __restrict__ out, int ctx, int L)
{
  __shared__ __align__(16) unsigned short Ps[4][32 * PSTR];
  __shared__ __align__(16) __half Ob[4][32 * OSTR];
  __shared__ float ML[4][32][2];

  const int bx   = blockIdx.x;
  const int kvh  = bx & 7;          // == XCD id under round-robin dispatch -> L2 affinity
  const int g    = (bx >> 3) & 3;
  const int qb   = bx >> 5;         // 0..31
  const int q0   = qb * 32;
  const int head = kvh * GRP + g;

  const int tid  = threadIdx.x;
  const int wave = tid >> 6;
  const int lane = tid & 63;
  const int col  = lane & 15;
  const int quad = lane >> 4;

  // Q fragments, pre-scaled by SCALE*log2(e) (softmax runs in exp2 domain)
  bf16x8 qf[2][4];
#pragma unroll
  for (int mt = 0; mt < 2; ++mt) {
    const float* qp = q + (size_t)(q0 + mt * 16 + col) * (NH * HD) + head * HD;
#pragma unroll
    for (int kt = 0; kt < 4; ++kt) {
      const float4 a = *(const float4*)(qp + kt * 32 + quad * 8);
      const float4 b = *(const float4*)(qp + kt * 32 + quad * 8 + 4);
      union { ushort8 u; bf16x8 h; } w;
      const float s = SCALE * LOG2E;
      w.u[0]=f2bf(a.x*s); w.u[1]=f2bf(a.y*s); w.u[2]=f2bf(a.z*s); w.u[3]=f2bf(a.w*s);
      w.u[4]=f2bf(b.x*s); w.u[5]=f2bf(b.y*s); w.u[6]=f2bf(b.z*s); w.u[7]=f2bf(b.w*s);
      qf[mt][kt] = w.h;
    }
  }

  f32x4 accO[2][8];
#pragma unroll
  for (int mt = 0; mt < 2; ++mt)
#pragma unroll
    for (int i = 0; i < 8; ++i) accO[mt][i] = (f32x4){0.f, 0.f, 0.f, 0.f};
  float mrow[2][4], lrow[2][4];
#pragma unroll
  for (int mt = 0; mt < 2; ++mt)
#pragma unroll
    for (int r = 0; r < 4; ++r) { mrow[mt][r] = -1e30f; lrow[mt][r] = 0.f; }

  const unsigned short* Kh = Kp + (size_t)kvh * L * HD;  // [l][d]
  const unsigned short* Vh = Vp + (size_t)kvh * HD * L;  // [d][l]
  unsigned short* pw = &Ps[wave][0];

  const int vis = ctx + q0 + 32;
  const int T   = (vis + 127) >> 7;

  const unsigned short* Kt = Kh + (size_t)(wave * 32) * HD;     // strip K base
  const unsigned short* Vt = Vh + wave * 32;                     // strip V base (col offset)

  for (int t = 0; t < T; ++t) {
    const int s0 = t * 128 + wave * 32;

    // ---- kf: 8 global b128 loads (strip-local K), then QK ----
    bf16x8 kf[4][2];
#pragma unroll
    for (int kt = 0; kt < 4; ++kt)
#pragma unroll
      for (int nt = 0; nt < 2; ++nt)
        kf[kt][nt] = *(const bf16x8*)(Kt + (size_t)(nt * 16 + col) * HD + kt * 32 + quad * 8);

    f32x4 S[2][2];
#pragma unroll
    for (int mt = 0; mt < 2; ++mt)
#pragma unroll
      for (int nt = 0; nt < 2; ++nt) S[mt][nt] = (f32x4){0.f, 0.f, 0.f, 0.f};
#pragma unroll
    for (int kt = 0; kt < 4; ++kt)
#pragma unroll
      for (int nt = 0; nt < 2; ++nt) {
        S[0][nt] = __builtin_amdgcn_mfma_f32_16x16x32_bf16(qf[0][kt], kf[kt][nt], S[0][nt], 0, 0, 0);
        S[1][nt] = __builtin_amdgcn_mfma_f32_16x16x32_bf16(qf[1][kt], kf[kt][nt], S[1][nt], 0, 0, 0);
      }

    // ---- vf: issue early; latency covered by mask+softmax ----
    bf16x8 vf[8];
#pragma unroll
    for (int nt = 0; nt < 8; ++nt)
      vf[nt] = *(const bf16x8*)(Vt + (size_t)(nt * 16 + col) * L + quad * 8);

    // ---- causal mask (wave-uniform guard) ----
    if (s0 + 31 > ctx + q0) {
#pragma unroll
      for (int mt = 0; mt < 2; ++mt)
#pragma unroll
        for (int r = 0; r < 4; ++r) {
          const int bound = ctx + q0 + mt * 16 + quad * 4 + r;
#pragma unroll
          for (int nt = 0; nt < 2; ++nt) {
            const int l = s0 + nt * 16 + col;
            if (l > bound) S[mt][nt][r] = -1e30f;
          }
        }
    }

    // ---- online softmax (exp2 domain) ----
    float alpha[2][4];
#pragma unroll
    for (int mt = 0; mt < 2; ++mt)
#pragma unroll
      for (int r = 0; r < 4; ++r) {
        float mx = fmaxf(S[mt][0][r], S[mt][1][r]);
        mx = dpp_max16(mx);
        const float mnew = fmaxf(mrow[mt][r], mx);
        alpha[mt][r] = __builtin_amdgcn_exp2f(mrow[mt][r] - mnew);
        float rs = 0.f;
#pragma unroll
        for (int nt = 0; nt < 2; ++nt) {
          const float p = __builtin_amdgcn_exp2f(S[mt][nt][r] - mnew);
          S[mt][nt][r] = p;
          rs += p;
        }
        rs = dpp_sum16(rs);
        lrow[mt][r] = lrow[mt][r] * alpha[mt][r] + rs;
        mrow[mt][r] = mnew;
      }
#pragma unroll
    for (int mt = 0; mt < 2; ++mt)
#pragma unroll
      for (int nt = 0; nt < 8; ++nt)
#pragma unroll
        for (int r = 0; r < 4; ++r)
          accO[mt][nt][r] *= alpha[mt][r];

    // ---- P: C layout -> LDS -> A layout (intra-wave, no barrier) ----
#pragma unroll
    for (int mt = 0; mt < 2; ++mt)
#pragma unroll
      for (int nt = 0; nt < 2; ++nt)
#pragma unroll
        for (int r = 0; r < 4; ++r)
          pw[(mt * 16 + quad * 4 + r) * PSTR + nt * 16 + col] = f2bf(S[mt][nt][r]);
    asm volatile("s_waitcnt lgkmcnt(0)" ::: "memory");

    bf16x8 pf[2];
    pf[0] = *(const bf16x8*)&pw[(col) * PSTR + quad * 8];
    pf[1] = *(const bf16x8*)&pw[(16 + col) * PSTR + quad * 8];

    // ---- O += P V (K-dim = 32 strip keys) ----
#pragma unroll
    for (int nt = 0; nt < 8; ++nt) {
      accO[0][nt] = __builtin_amdgcn_mfma_f32_16x16x32_bf16(pf[0], vf[nt], accO[0][nt], 0, 0, 0);
      accO[1][nt] = __builtin_amdgcn_mfma_f32_16x16x32_bf16(pf[1], vf[nt], accO[1][nt], 0, 0, 0);
    }

    Kt += 128 * HD;
    Vt += 128;
  }

  // ---- merge the 4 waves' partial (m, l, O) ----
  if (col == 0) {
#pragma unroll
    for (int mt = 0; mt < 2; ++mt)
#pragma unroll
      for (int r = 0; r < 4; ++r) {
        const int row = mt * 16 + quad * 4 + r;
        ML[wave][row][0] = mrow[mt][r];
        ML[wave][row][1] = lrow[mt][r];
      }
  }
#pragma unroll
  for (int mt = 0; mt < 2; ++mt)
#pragma unroll
    for (int nt = 0; nt < 8; ++nt)
#pragma unroll
      for (int r = 0; r < 4; ++r)
        Ob[wave][(mt * 16 + quad * 4 + r) * OSTR + nt * 16 + col] = __float2half(accO[mt][nt][r]);
  __syncthreads();

  const int row = wave * 8 + (lane >> 3);
  const int dc  = (lane & 7) * 16;
  float mw[4], lw[4];
  float mstar = -1e30f;
#pragma unroll
  for (int w = 0; w < 4; ++w) {
    mw[w] = ML[w][row][0];
    lw[w] = ML[w][row][1];
    mstar = fmaxf(mstar, mw[w]);
  }
  float aw[4], lsum = 0.f;
#pragma unroll
  for (int w = 0; w < 4; ++w) {
    aw[w] = __builtin_amdgcn_exp2f(mw[w] - mstar);
    lsum += aw[w] * lw[w];
  }
  const float inv = 1.0f / lsum;
  float acc[16];
#pragma unroll
  for (int j = 0; j < 16; ++j) acc[j] = 0.f;
#pragma unroll
  for (int w = 0; w < 4; ++w) {
    const __half* ob = &Ob[w][row * OSTR + dc];
#pragma unroll
    for (int j = 0; j < 16; ++j) acc[j] += aw[w] * __half2float(ob[j]);
  }
  float* orow = out + (size_t)(q0 + row) * (NH * HD) + head * HD + dc;
#pragma unroll
  for (int i = 0; i < 4; ++i) {
    float4 o;
    o.x = acc[i*4+0] * inv; o.y = acc[i*4+1] * inv;
    o.z = acc[i*4+2] * inv; o.w = acc[i*4+3] * inv;
    *(float4*)(orow + i * 4) = o;
  }
}

extern "C" void kernel_launch(void* const* d_in, const int* in_sizes, int n_in,
                              void* d_out, int out_size, void* d_ws, size_t ws_size,
                              hipStream_t stream) {
  const float* q  = (const float*)d_in[0];
  const float* k  = (const float*)d_in[1];
  const float* v  = (const float*)d_in[2];
  const float* kc = (const float*)d_in[3];
  const float* vc = (const float*)d_in[4];
  // d_in[5] slot_mapping: scatter targets disjoint from context_slots -> no output effect
  const int* ctx_slots = (const int*)d_in[6];
  float* out = (float*)d_out;

  const int seq = in_sizes[0] / (NH * HD);
  const int ctx = in_sizes[6];
  const int L   = ctx + seq;                                 // 4096

  unsigned short* Kp = (unsigned short*)d_ws;                // 8.4 MB
  unsigned short* Vp = Kp + (size_t)NKVH * L * HD;           // +8.4 MB

  const int kblocks = (NKVH * L * 8) / 256;                  // 1024
  const int vblocks = NKVH * (L / 64);                       // 512
  prep_kernel<<<kblocks + vblocks, 256, 0, stream>>>(k, v, kc, vc, ctx_slots,
                                                     Kp, Vp, ctx, L, kblocks);

  const int nblocks = (seq / 32) * GRP * NKVH;               // 1024
  attn_kernel<<<nblocks, 256, 0, stream>>>(q, Kp, Vp, out, ctx, L);
}

// Round 6
// 259.182 us; speedup vs baseline: 1.2929x; 1.2929x over previous
//
#include <hip/hip_runtime.h>

#define NH 32
#define NKVH 8
#define HD 128
#define GRP 4
#define SCALE 0.08838834764831845f
#define LOG2E 1.4426950408889634f

typedef __attribute__((ext_vector_type(8))) __bf16 bf16x8;
typedef __attribute__((ext_vector_type(4))) float f32x4;
typedef __attribute__((ext_vector_type(8))) unsigned short ushort8;

__device__ inline unsigned short f2bf(float x) {
  unsigned int u = __float_as_uint(x);
  u += 0x7fffu + ((u >> 16) & 1u);   // RNE
  return (unsigned short)(u >> 16);
}

__device__ inline float dpp_max16(float x) {
  x = fmaxf(x, __int_as_float(__builtin_amdgcn_mov_dpp(__float_as_int(x), 0xB1, 0xF, 0xF, true)));
  x = fmaxf(x, __int_as_float(__builtin_amdgcn_mov_dpp(__float_as_int(x), 0x4E, 0xF, 0xF, true)));
  x = fmaxf(x, __int_as_float(__builtin_amdgcn_mov_dpp(__float_as_int(x), 0x141, 0xF, 0xF, true)));
  x = fmaxf(x, __int_as_float(__builtin_amdgcn_mov_dpp(__float_as_int(x), 0x140, 0xF, 0xF, true)));
  return x;
}
__device__ inline float dpp_sum16(float x) {
  x += __int_as_float(__builtin_amdgcn_mov_dpp(__float_as_int(x), 0xB1, 0xF, 0xF, true));
  x += __int_as_float(__builtin_amdgcn_mov_dpp(__float_as_int(x), 0x4E, 0xF, 0xF, true));
  x += __int_as_float(__builtin_amdgcn_mov_dpp(__float_as_int(x), 0x141, 0xF, 0xF, true));
  x += __int_as_float(__builtin_amdgcn_mov_dpp(__float_as_int(x), 0x140, 0xF, 0xF, true));
  return x;
}

__device__ inline void load_lds16(const unsigned short* g, unsigned short* l) {
  __builtin_amdgcn_global_load_lds((const __attribute__((address_space(1))) unsigned int*)g,
                                   (__attribute__((address_space(3))) unsigned int*)l, 16, 0, 0);
}

#define PSTR 40    // P row stride (32 keys + 8 pad)
#define OMSTR 132  // fp32 merge-buffer row stride

// ---------------- fused pre-pass (layouts identical to R3 — verified) ----------------
// K ws: [kvh][tile][r=l&63][c'=(d>>3)^(r&7)][d&7]  (8192 elems / 16KB per 64-key tile)
// V ws: [kvh][tile][d][c'=((l&63)>>3)^(d&7)][l&7]  (transposed)
__global__ __launch_bounds__(256) void prep_kernel(
    const float* __restrict__ k, const float* __restrict__ v,
    const float* __restrict__ kc, const float* __restrict__ vc,
    const int* __restrict__ slots,
    unsigned short* __restrict__ Kws, unsigned short* __restrict__ Vws,
    int ctx, int L, int kblocks)
{
  if ((int)blockIdx.x < kblocks) {
    const int idx = blockIdx.x * 256 + threadIdx.x;
    const int L8  = L * 8;
    const int kvh = idx / L8;
    const int rem = idx - kvh * L8;
    const int l   = rem >> 3;
    const int c16 = idx & 7;
    const float* src = (l < ctx)
        ? kc + ((size_t)slots[l] * NKVH + kvh) * HD + c16 * 16
        : k + (size_t)(l - ctx) * (NKVH * HD) + kvh * HD + c16 * 16;
    float4 f[4];
#pragma unroll
    for (int i = 0; i < 4; ++i) f[i] = ((const float4*)src)[i];
    unsigned short* tile = Kws + (size_t)kvh * L * HD + (size_t)(l >> 6) * 8192;
    const int r  = l & 63;
    const int c0 = (2 * c16) ^ (r & 7);
    const int c1 = (2 * c16 + 1) ^ (r & 7);
    ushort8 w0, w1;
    w0[0]=f2bf(f[0].x); w0[1]=f2bf(f[0].y); w0[2]=f2bf(f[0].z); w0[3]=f2bf(f[0].w);
    w0[4]=f2bf(f[1].x); w0[5]=f2bf(f[1].y); w0[6]=f2bf(f[1].z); w0[7]=f2bf(f[1].w);
    w1[0]=f2bf(f[2].x); w1[1]=f2bf(f[2].y); w1[2]=f2bf(f[2].z); w1[3]=f2bf(f[2].w);
    w1[4]=f2bf(f[3].x); w1[5]=f2bf(f[3].y); w1[6]=f2bf(f[3].z); w1[7]=f2bf(f[3].w);
    *(ushort8*)&tile[r * 128 + c0 * 8] = w0;
    *(ushort8*)&tile[r * 128 + c1 * 8] = w1;
  } else {
    __shared__ __align__(16) unsigned short VT[128 * 72];
    const int b   = blockIdx.x - kblocks;
    const int ntv = L >> 6;
    const int kvh = b / ntv;
    const int t   = b - kvh * ntv;
    const int tid = threadIdx.x;
    const int l   = tid >> 2;
    const int ds  = tid & 3;
    const int lg  = t * 64 + l;
    const float* sp = (lg < ctx)
        ? vc + ((size_t)slots[lg] * NKVH + kvh) * HD
        : v + (size_t)(lg - ctx) * (NKVH * HD) + kvh * HD;
    sp += ds * 32;
    float4 f[8];
#pragma unroll
    for (int i = 0; i < 8; ++i) f[i] = ((const float4*)sp)[i];
    const int c  = l >> 3;
    const int lo = l & 7;
#pragma unroll
    for (int i = 0; i < 8; ++i) {
      const int d0 = ds * 32 + i * 4;
      VT[(d0+0)*72 + ((c ^ ((d0+0)&7)) << 3) + lo] = f2bf(f[i].x);
      VT[(d0+1)*72 + ((c ^ ((d0+1)&7)) << 3) + lo] = f2bf(f[i].y);
      VT[(d0+2)*72 + ((c ^ ((d0+2)&7)) << 3) + lo] = f2bf(f[i].z);
      VT[(d0+3)*72 + ((c ^ ((d0+3)&7)) << 3) + lo] = f2bf(f[i].w);
    }
    __syncthreads();
    unsigned short* dst = Vws + (size_t)kvh * L * HD + (size_t)t * 8192;
    const int d   = tid >> 1;
    const int seg = tid & 1;
#pragma unroll
    for (int i = 0; i < 4; ++i)
      *(ushort8*)(dst + d * 64 + seg * 32 + i * 8) = *(const ushort8*)&VT[d * 72 + seg * 32 + i * 8];
  }
}

// ---------------- attention: 512 thr = 8 waves = 4 m-groups x 2 key-splits ----------------
// Block covers 128 q-rows; wave (mg,ks): rows q0+32mg..+31, keys 64t+32ks..+31 per round.
// R3's DMA double-buffer skeleton; in-block fp32 flash-decoding merge at the end.
__global__ __launch_bounds__(512, 2) void attn_kernel(
    const float* __restrict__ q,
    const unsigned short* __restrict__ Kp, const unsigned short* __restrict__ Vp,
    float* __restrict__ out, int ctx, int L)
{
  __shared__ __align__(16) union {
    struct {
      unsigned short Ks[2][8192];
      unsigned short Vs[2][8192];
      unsigned short Ps[8][32 * PSTR];
    } r;                                  // 84.5 KB, live during rounds
    float Om[4][32 * OMSTR];              // 67.6 KB, live during merge only
  } U;
  __shared__ float ML2[4][32][2];

  const int bx   = blockIdx.x;
  const int kvh  = bx & 7;                // == XCD under round-robin -> L2 affinity
  const int g    = (bx >> 3) & 3;
  const int qb   = bx >> 5;               // 0..7
  const int q0   = qb * 128;
  const int head = kvh * GRP + g;

  const int tid  = threadIdx.x;
  const int wave = tid >> 6;              // 0..7
  const int lane = tid & 63;
  const int col  = lane & 15;
  const int quad = lane >> 4;
  const int mg   = wave >> 1;             // m-group 0..3
  const int ks   = wave & 1;              // key-split 0..1
  const int rbase = q0 + mg * 32;

  // Q fragments (A layout), pre-scaled by SCALE*log2(e)
  bf16x8 qf[2][4];
#pragma unroll
  for (int mt = 0; mt < 2; ++mt) {
    const float* qp = q + (size_t)(rbase + mt * 16 + col) * (NH * HD) + head * HD;
#pragma unroll
    for (int kt = 0; kt < 4; ++kt) {
      const float4 a = *(const float4*)(qp + kt * 32 + quad * 8);
      const float4 b = *(const float4*)(qp + kt * 32 + quad * 8 + 4);
      union { ushort8 u; bf16x8 h; } w;
      const float s = SCALE * LOG2E;
      w.u[0]=f2bf(a.x*s); w.u[1]=f2bf(a.y*s); w.u[2]=f2bf(a.z*s); w.u[3]=f2bf(a.w*s);
      w.u[4]=f2bf(b.x*s); w.u[5]=f2bf(b.y*s); w.u[6]=f2bf(b.z*s); w.u[7]=f2bf(b.w*s);
      qf[mt][kt] = w.h;
    }
  }

  f32x4 accO[2][8];
#pragma unroll
  for (int mt = 0; mt < 2; ++mt)
#pragma unroll
    for (int i = 0; i < 8; ++i) accO[mt][i] = (f32x4){0.f, 0.f, 0.f, 0.f};
  float mrow[2][4], lrow[2][4];
#pragma unroll
  for (int mt = 0; mt < 2; ++mt)
#pragma unroll
    for (int r = 0; r < 4; ++r) { mrow[mt][r] = -1e30f; lrow[mt][r] = 0.f; }

  const size_t kvbase = (size_t)kvh * L * HD;
  const int T = (ctx + q0 + 128) >> 6;    // 64-key rounds

  // Per round: waves 0-3 DMA the 16KB K tile, waves 4-7 the 16KB V tile (4x 1KB chunks each).
  auto dma_tile = [&](int t, int b) {
    const unsigned short* src = ((wave < 4) ? Kp : Vp) + kvbase + (size_t)t * 8192;
    unsigned short* dst = (wave < 4) ? U.r.Ks[b] : U.r.Vs[b];
    const int w4 = wave & 3;
#pragma unroll
    for (int j = 0; j < 4; ++j) {
      const int ch = w4 * 4 + j;
      load_lds16(src + ch * 512 + lane * 8, dst + ch * 512);
    }
  };

  dma_tile(0, 0);
  unsigned short* pw = U.r.Ps[wave];

  for (int t = 0; t < T; ++t) {
    __syncthreads();                       // drains round-t DMA; frees other buffer
    if (t + 1 < T) dma_tile(t + 1, (t + 1) & 1);

    const unsigned short* Kb = U.r.Ks[t & 1];
    const unsigned short* Vb = U.r.Vs[t & 1];
    const int s0 = t * 64 + ks * 32;

    // ---- S = Q K^T over this wave's 32-key half ----
    f32x4 S[2][2];
#pragma unroll
    for (int mt = 0; mt < 2; ++mt)
#pragma unroll
      for (int nt = 0; nt < 2; ++nt) S[mt][nt] = (f32x4){0.f, 0.f, 0.f, 0.f};
#pragma unroll
    for (int kt = 0; kt < 4; ++kt)
#pragma unroll
      for (int nt = 0; nt < 2; ++nt) {
        const int row = ks * 32 + nt * 16 + col;
        const bf16x8 kf = *(const bf16x8*)&Kb[row * 128 + (((kt * 4 + quad) ^ (row & 7)) << 3)];
        S[0][nt] = __builtin_amdgcn_mfma_f32_16x16x32_bf16(qf[0][kt], kf, S[0][nt], 0, 0, 0);
        S[1][nt] = __builtin_amdgcn_mfma_f32_16x16x32_bf16(qf[1][kt], kf, S[1][nt], 0, 0, 0);
      }

    // ---- causal mask (wave-uniform guard) ----
    if (s0 + 31 > ctx + rbase) {
#pragma unroll
      for (int mt = 0; mt < 2; ++mt)
#pragma unroll
        for (int r = 0; r < 4; ++r) {
          const int bound = ctx + rbase + mt * 16 + quad * 4 + r;
#pragma unroll
          for (int nt = 0; nt < 2; ++nt) {
            const int l = s0 + nt * 16 + col;
            if (l > bound) S[mt][nt][r] = -1e30f;
          }
        }
    }

    // ---- online softmax (exp2 domain) ----
#pragma unroll
    for (int mt = 0; mt < 2; ++mt) {
      float alpha[4];
#pragma unroll
      for (int r = 0; r < 4; ++r) {
        float mx = fmaxf(S[mt][0][r], S[mt][1][r]);
        mx = dpp_max16(mx);
        const float mnew = fmaxf(mrow[mt][r], mx);
        alpha[r] = __builtin_amdgcn_exp2f(mrow[mt][r] - mnew);
        float rs = 0.f;
#pragma unroll
        for (int nt = 0; nt < 2; ++nt) {
          const float p = __builtin_amdgcn_exp2f(S[mt][nt][r] - mnew);
          S[mt][nt][r] = p;
          rs += p;
        }
        rs = dpp_sum16(rs);
        lrow[mt][r] = lrow[mt][r] * alpha[r] + rs;
        mrow[mt][r] = mnew;
      }
#pragma unroll
      for (int nt = 0; nt < 8; ++nt)
#pragma unroll
        for (int r = 0; r < 4; ++r)
          accO[mt][nt][r] *= alpha[r];
    }

    // ---- P: C layout -> LDS -> A layout (intra-wave, no barrier) ----
#pragma unroll
    for (int mt = 0; mt < 2; ++mt)
#pragma unroll
      for (int nt = 0; nt < 2; ++nt)
#pragma unroll
        for (int r = 0; r < 4; ++r)
          pw[(mt * 16 + quad * 4 + r) * PSTR + nt * 16 + col] = f2bf(S[mt][nt][r]);
    asm volatile("s_waitcnt lgkmcnt(0)" ::: "memory");

    bf16x8 pf[2];
    pf[0] = *(const bf16x8*)&pw[col * PSTR + quad * 8];
    pf[1] = *(const bf16x8*)&pw[(16 + col) * PSTR + quad * 8];

    // ---- O += P V (K-dim = 32 keys); vf shared by both m-tiles ----
#pragma unroll
    for (int nt = 0; nt < 8; ++nt) {
      const int d = nt * 16 + col;
      const bf16x8 vf = *(const bf16x8*)&Vb[d * 64 + (((ks * 4 + quad) ^ (d & 7)) << 3)];
      accO[0][nt] = __builtin_amdgcn_mfma_f32_16x16x32_bf16(pf[0], vf, accO[0][nt], 0, 0, 0);
      accO[1][nt] = __builtin_amdgcn_mfma_f32_16x16x32_bf16(pf[1], vf, accO[1][nt], 0, 0, 0);
    }
  }

  // ---- in-block merge of the two key-split partials (fp32) ----
  __syncthreads();                         // rounds done; K/V/P area reusable as Om
  if (ks == 1) {
#pragma unroll
    for (int mt = 0; mt < 2; ++mt)
#pragma unroll
      for (int r = 0; r < 4; ++r) {
        const int row = mt * 16 + quad * 4 + r;
        if (col == 0) { ML2[mg][row][0] = mrow[mt][r]; ML2[mg][row][1] = lrow[mt][r]; }
#pragma unroll
        for (int nt = 0; nt < 8; ++nt)
          U.Om[mg][row * OMSTR + nt * 16 + col] = accO[mt][nt][r];
      }
  }
  __syncthreads();
  if (ks == 0) {
#pragma unroll
    for (int mt = 0; mt < 2; ++mt)
#pragma unroll
      for (int r = 0; r < 4; ++r) {
        const int row = mt * 16 + quad * 4 + r;
        const float m1 = ML2[mg][row][0];
        const float l1 = ML2[mg][row][1];
        const float ms = fmaxf(mrow[mt][r], m1);
        const float a0 = __builtin_amdgcn_exp2f(mrow[mt][r] - ms);
        const float a1 = __builtin_amdgcn_exp2f(m1 - ms);
        const float inv = 1.0f / (a0 * lrow[mt][r] + a1 * l1);
        const float ga0 = a0 * inv, ga1 = a1 * inv;
        float* orow = out + (size_t)(rbase + row) * (NH * HD) + head * HD;
#pragma unroll
        for (int nt = 0; nt < 8; ++nt)
          orow[nt * 16 + col] = ga0 * accO[mt][nt][r] + ga1 * U.Om[mg][row * OMSTR + nt * 16 + col];
      }
  }
}

extern "C" void kernel_launch(void* const* d_in, const int* in_sizes, int n_in,
                              void* d_out, int out_size, void* d_ws, size_t ws_size,
                              hipStream_t stream) {
  const float* q  = (const float*)d_in[0];
  const float* k  = (const float*)d_in[1];
  const float* v  = (const float*)d_in[2];
  const float* kc = (const float*)d_in[3];
  const float* vc = (const float*)d_in[4];
  // d_in[5] slot_mapping: scatter targets disjoint from context_slots -> no output effect
  const int* ctx_slots = (const int*)d_in[6];
  float* out = (float*)d_out;

  const int seq = in_sizes[0] / (NH * HD);
  const int ctx = in_sizes[6];
  const int L   = ctx + seq;                                 // 4096

  unsigned short* Kp = (unsigned short*)d_ws;                // 8.4 MB
  unsigned short* Vp = Kp + (size_t)NKVH * L * HD;           // +8.4 MB

  const int kblocks = (NKVH * L * 8) / 256;                  // 1024
  const int vblocks = NKVH * (L >> 6);                       // 512
  prep_kernel<<<kblocks + vblocks, 256, 0, stream>>>(k, v, kc, vc, ctx_slots,
                                                     Kp, Vp, ctx, L, kblocks);

  const int nblocks = (seq / 128) * GRP * NKVH;              // 256
  attn_kernel<<<nblocks, 512, 0, stream>>>(q, Kp, Vp, out, ctx, L);
}